// Round 1
// baseline (39.521 us; speedup 1.0000x reference)
//
#include <hip/hip_runtime.h>

// DivEncLayer: per (b,q): h = elu(x[b,q*8:+8] @ W1[q] + b1[q]); LN(h); out = h@W2[q]+b2[q]
// Q=128, S=8, U=32, B=16384. out[b*128+q], fp32 everywhere.
//
// Folding: LN+Dense2 -> out = rsqrt(var+eps)*(dot(h,g2) - mu*G) + C
//   g2[u] = gamma[q,u]*W2[q,u], G = sum(g2), C = sum(beta*W2) + b2[q]
//
// Mapping: block = 256 thr = 4 waves. Wave w owns q = blockIdx.y*4+w (W1 LDS
// reads wave-uniform -> broadcast, conflict-free). Block covers 128 b-rows;
// each thread computes 2 b's (amortizes W1 LDS traffic). Output staged in
// padded LDS (stride 5) then written as float4 per b-row.

#define S 8
#define U 32
#define QTOT 128

__device__ __forceinline__ float4 fma4(float s, float4 a, float4 c) {
    c.x = fmaf(s, a.x, c.x);
    c.y = fmaf(s, a.y, c.y);
    c.z = fmaf(s, a.z, c.z);
    c.w = fmaf(s, a.w, c.w);
    return c;
}

__device__ __forceinline__ float elu1(float v) {
    return v > 0.f ? v : __expf(v) - 1.f;
}

// ELU + mean/var + folded LN*Dense2 for one 32-wide row held as float4 h[8]
__device__ __forceinline__ float finish_row(float4 h[8], const float4* __restrict__ g4,
                                            float G, float C) {
    #pragma unroll
    for (int i = 0; i < 8; ++i) {
        h[i].x = elu1(h[i].x);
        h[i].y = elu1(h[i].y);
        h[i].z = elu1(h[i].z);
        h[i].w = elu1(h[i].w);
    }
    float sum = 0.f, ss = 0.f;
    #pragma unroll
    for (int i = 0; i < 8; ++i) {
        sum += (h[i].x + h[i].y) + (h[i].z + h[i].w);
        ss = fmaf(h[i].x, h[i].x, ss);
        ss = fmaf(h[i].y, h[i].y, ss);
        ss = fmaf(h[i].z, h[i].z, ss);
        ss = fmaf(h[i].w, h[i].w, ss);
    }
    float mu  = sum * 0.03125f;                    // /32
    float var = fmaf(-mu, mu, ss * 0.03125f);      // E[h^2]-mu^2
    float inv = rsqrtf(var + 1e-3f);
    float dot = 0.f;
    #pragma unroll
    for (int i = 0; i < 8; ++i) {
        float4 g = g4[i];
        dot = fmaf(h[i].x, g.x, dot);
        dot = fmaf(h[i].y, g.y, dot);
        dot = fmaf(h[i].z, g.z, dot);
        dot = fmaf(h[i].w, g.w, dot);
    }
    return fmaf(inv, fmaf(-mu, G, dot), C);
}

__global__ __launch_bounds__(256) void divenc_kernel(
    const float* __restrict__ x,      // (B, 1024)
    const float* __restrict__ W1,     // (128, 8, 32)
    const float* __restrict__ b1,     // (128, 32)
    const float* __restrict__ gamma,  // (128, 32)
    const float* __restrict__ beta,   // (128, 32)
    const float* __restrict__ W2,     // (128, 32)
    const float* __restrict__ b2,     // (128,)
    float* __restrict__ out)          // (B, 128)
{
    __shared__ float lw1[4 * S * U];   // 1024 floats: W1 for 4 q's
    __shared__ float lb1[4 * U];       // 128
    __shared__ float lg2[4 * U];       // 128 (gamma*W2)
    __shared__ float lout[128 * 5];    // 128 b-rows x 4 q, stride 5 (pad)

    const int tid   = threadIdx.x;
    const int w     = tid >> 6;        // wave 0..3
    const int ln    = tid & 63;
    const int btile = blockIdx.x;      // 0..B/128-1 (fast-varying)
    const int qtile = blockIdx.y;      // 0..31
    const int q     = qtile * 4 + w;
    const int b0    = btile * 128;

    // ---- early independent x loads (2 b's per thread, 2 float4 each) ----
    const float4* xa_p = (const float4*)(x + (size_t)(b0 + ln)      * 1024 + q * S);
    const float4* xb_p = (const float4*)(x + (size_t)(b0 + ln + 64) * 1024 + q * S);
    float4 xa0 = xa_p[0], xa1 = xa_p[1];
    float4 xb0 = xb_p[0], xb1 = xb_p[1];

    // ---- stage W1 tile (256 float4, one per thread) + b1 ----
    {
        const float4* w1g = (const float4*)(W1 + (size_t)qtile * 4 * S * U);
        ((float4*)lw1)[tid] = w1g[tid];
        if (tid < 32)
            ((float4*)lb1)[tid] = ((const float4*)(b1 + (size_t)qtile * 4 * U))[tid];
    }

    // ---- per-wave scalars: g2[u], G=sum g2, C=sum(beta*W2)+b2 ----
    const int u   = ln & 31;
    float g2v = gamma[q * U + u] * W2[q * U + u];
    float bwv = beta [q * U + u] * W2[q * U + u];
    if (ln < 32) lg2[w * U + u] = g2v;
    float Gs = g2v, Cs = bwv;
    #pragma unroll
    for (int m = 1; m < 32; m <<= 1) {
        Gs += __shfl_xor(Gs, m);
        Cs += __shfl_xor(Cs, m);
    }
    const float G = Gs;
    const float C = Cs + b2[q];

    __syncthreads();

    // ---- Dense1 for both b's, sharing each W1 read ----
    float xs0[8] = {xa0.x, xa0.y, xa0.z, xa0.w, xa1.x, xa1.y, xa1.z, xa1.w};
    float xs1[8] = {xb0.x, xb0.y, xb0.z, xb0.w, xb1.x, xb1.y, xb1.z, xb1.w};

    float4 h0[8], h1[8];
    #pragma unroll
    for (int u4 = 0; u4 < 8; ++u4) {
        float4 bv = ((const float4*)lb1)[w * 8 + u4];
        h0[u4] = bv;
        h1[u4] = bv;
    }
    const float4* w1q = ((const float4*)lw1) + w * (S * U / 4);   // [8 s][8 u4]
    #pragma unroll
    for (int s = 0; s < 8; ++s) {
        #pragma unroll
        for (int u4 = 0; u4 < 8; ++u4) {
            float4 wv = w1q[s * 8 + u4];
            h0[u4] = fma4(xs0[s], wv, h0[u4]);
            h1[u4] = fma4(xs1[s], wv, h1[u4]);
        }
    }

    // ---- ELU + LN + Dense2 (folded) ----
    const float4* g4 = ((const float4*)lg2) + w * 8;
    float r0 = finish_row(h0, g4, G, C);
    float r1 = finish_row(h1, g4, G, C);

    // ---- gather to LDS, write float4 per b-row ----
    lout[ln * 5 + w]        = r0;
    lout[(ln + 64) * 5 + w] = r1;
    __syncthreads();

    if (tid < 128) {
        float4 o;
        o.x = lout[tid * 5 + 0];
        o.y = lout[tid * 5 + 1];
        o.z = lout[tid * 5 + 2];
        o.w = lout[tid * 5 + 3];
        *(float4*)(out + (size_t)(b0 + tid) * QTOT + qtile * 4) = o;
    }
}

extern "C" void kernel_launch(void* const* d_in, const int* in_sizes, int n_in,
                              void* d_out, int out_size, void* d_ws, size_t ws_size,
                              hipStream_t stream) {
    const float* x     = (const float*)d_in[0];
    const float* W1    = (const float*)d_in[1];
    const float* b1    = (const float*)d_in[2];
    const float* gamma = (const float*)d_in[3];
    const float* beta  = (const float*)d_in[4];
    const float* W2    = (const float*)d_in[5];
    const float* b2    = (const float*)d_in[6];
    float* out = (float*)d_out;

    const int B = in_sizes[0] / (QTOT * S);   // 16384
    dim3 grid(B / 128, QTOT / 4);             // (128, 32)
    divenc_kernel<<<grid, 256, 0, stream>>>(x, W1, b1, gamma, beta, W2, b2, out);
}

// Round 2
// 31.427 us; speedup vs baseline: 1.2576x; 1.2576x over previous
//
#include <hip/hip_runtime.h>

// DivEncLayer via MFMA. Per (b,q): h = elu(x[b,q*8:+8]@W1[q] + b1[q]); LN; out=h@W2[q]+b2[q].
// B=16384, Q=128, S=8, U=32.
//
// MFMA mapping (v_mfma_f32_32x32x16_bf16, swapped operands so LN axis is lane-local):
//   A[u][k] = W1[q][k][u] (k<8, else 0)   M=32 u's
//   B[k][b'] = x[b0+b'][q*8+k]            N=32 b-rows, K=16 (k>=8 unused: A=0 there)
//   D: col=lane&31 -> b', row=(reg&3)+8*(reg>>2)+4*(lane>>5) -> u  [HW-verified layout]
// bf16 split for ~fp32 accuracy: D = xhi*whi + xlo*whi + xhi*wlo, C-in = b1 (fp32, exact).
// LN+Dense2 folded: out = rsqrt(var+eps)*(dot(e,g2) - mu*G) + C,
//   g2=gamma*W2, G=sum g2, C=sum(beta*W2)+b2.
//
// Block = 256 thr = 4 waves = 4 consecutive q. Loops 8 b-tiles of 64 rows,
// x prefetched 1 iter ahead. Grid (32 btile-groups, 32 qtiles) = 1024 blocks.

typedef __attribute__((ext_vector_type(8))) short short8;    // 8 bf16 (4 VGPRs)
typedef __attribute__((ext_vector_type(16))) float f32x16;

__device__ __forceinline__ short fbits(__bf16 b) { return __builtin_bit_cast(short, b); }

__device__ __forceinline__ float elu1(float v) {
    return v > 0.f ? v : __expf(v) - 1.f;
}

__global__ __launch_bounds__(256) void divenc_mfma(
    const float* __restrict__ x,      // (16384, 1024)
    const float* __restrict__ W1,     // (128, 8, 32)
    const float* __restrict__ b1,     // (128, 32)
    const float* __restrict__ gamma,  // (128, 32)
    const float* __restrict__ beta,   // (128, 32)
    const float* __restrict__ W2,     // (128, 32)
    const float* __restrict__ b2,     // (128,)
    float* __restrict__ out)          // (16384, 128)
{
    __shared__ float lout[2][64 * 5];  // double-buffered, padded stride 5

    const int tid  = threadIdx.x;
    const int w    = tid >> 6;         // wave -> q offset
    const int ln   = tid & 63;
    const int lo5  = ln & 31;
    const int half = ln >> 5;
    const int qt   = blockIdx.y;       // 0..31
    const int q    = qt * 4 + w;
    const int bx   = blockIdx.x;       // 0..31

    // ---- per-q setup: A fragment (W1^T), hi/lo split ----
    short8 whi = {}, wlo = {};
    if (half == 0) {
        #pragma unroll
        for (int j = 0; j < 8; ++j) {
            float f = W1[q * 256 + j * 32 + lo5];   // A[u=lo5][k=j]
            __bf16 h = (__bf16)f;
            whi[j] = fbits(h);
            wlo[j] = fbits((__bf16)(f - (float)h));
        }
    }

    // ---- D-reg u mapping: u(r) = (r&3) + 8*(r>>2) + 4*half ----
    f32x16 biasr;
    float g2r[16];
    float G, C;
    {
        float gs = 0.f, cs = 0.f;
        #pragma unroll
        for (int r = 0; r < 16; ++r) {
            int u = (r & 3) + 8 * (r >> 2) + 4 * half;
            float w2 = W2[q * 32 + u];
            g2r[r]   = gamma[q * 32 + u] * w2;
            biasr[r] = b1[q * 32 + u];
            gs += g2r[r];
            cs += beta[q * 32 + u] * w2;
        }
        gs += __shfl_xor(gs, 32);
        cs += __shfl_xor(cs, 32);
        G = gs;
        C = cs + b2[q];
    }

    const float* xq = x + q * 8;

    // prime first tile's x (8 floats per lane = this lane's row)
    float4 xa, xb;
    {
        const float* p = xq + (size_t)(bx * 512 + ln) * 1024;
        xa = ((const float4*)p)[0];
        xb = ((const float4*)p)[1];
    }

    #pragma unroll 1
    for (int it = 0; it < 8; ++it) {
        const int b0 = (bx * 8 + it) * 64;

        // prefetch next tile (last iter re-reads current: L2-hot, discarded)
        const int bn = (it < 7) ? b0 + 64 : b0;
        const float* pn = xq + (size_t)(bn + ln) * 1024;
        float4 na = ((const float4*)pn)[0];
        float4 nb = ((const float4*)pn)[1];

        // convert current rows to bf16 hi/lo
        float xf[8] = {xa.x, xa.y, xa.z, xa.w, xb.x, xb.y, xb.z, xb.w};
        short8 xhi, xlo;
        #pragma unroll
        for (int j = 0; j < 8; ++j) {
            __bf16 h = (__bf16)xf[j];
            xhi[j] = fbits(h);
            xlo[j] = fbits((__bf16)(xf[j] - (float)h));
        }

        // tile1 B-frag: rows 32..63 pulled into lanes 0..31 (upper lanes garbage-ok, A=0 there)
        int4 hI = __builtin_bit_cast(int4, xhi);
        int4 lI = __builtin_bit_cast(int4, xlo);
        int4 h1, l1;
        h1.x = __shfl_xor(hI.x, 32); h1.y = __shfl_xor(hI.y, 32);
        h1.z = __shfl_xor(hI.z, 32); h1.w = __shfl_xor(hI.w, 32);
        l1.x = __shfl_xor(lI.x, 32); l1.y = __shfl_xor(lI.y, 32);
        l1.z = __shfl_xor(lI.z, 32); l1.w = __shfl_xor(lI.w, 32);
        short8 xhi1 = __builtin_bit_cast(short8, h1);
        short8 xlo1 = __builtin_bit_cast(short8, l1);

        // Dense1 on matrix pipe: 3-MFMA bf16 split, C-in = fp32 bias
        f32x16 acc0 = __builtin_amdgcn_mfma_f32_32x32x16_bf16(whi, xhi, biasr, 0, 0, 0);
        acc0 = __builtin_amdgcn_mfma_f32_32x32x16_bf16(whi, xlo, acc0, 0, 0, 0);
        acc0 = __builtin_amdgcn_mfma_f32_32x32x16_bf16(wlo, xhi, acc0, 0, 0, 0);
        f32x16 acc1 = __builtin_amdgcn_mfma_f32_32x32x16_bf16(whi, xhi1, biasr, 0, 0, 0);
        acc1 = __builtin_amdgcn_mfma_f32_32x32x16_bf16(whi, xlo1, acc1, 0, 0, 0);
        acc1 = __builtin_amdgcn_mfma_f32_32x32x16_bf16(wlo, xhi1, acc1, 0, 0, 0);

        // ELU + LN + folded Dense2 per tile
        float res0, res1;
        {
            float sum = 0.f, ss = 0.f, dot = 0.f;
            #pragma unroll
            for (int r = 0; r < 16; ++r) {
                float e = elu1(acc0[r]);
                sum += e; ss = fmaf(e, e, ss); dot = fmaf(e, g2r[r], dot);
            }
            sum += __shfl_xor(sum, 32);
            ss  += __shfl_xor(ss, 32);
            dot += __shfl_xor(dot, 32);
            float mu  = sum * 0.03125f;
            float var = fmaf(-mu, mu, ss * 0.03125f);
            float inv = rsqrtf(var + 1e-3f);
            res0 = fmaf(inv, fmaf(-mu, G, dot), C);
        }
        {
            float sum = 0.f, ss = 0.f, dot = 0.f;
            #pragma unroll
            for (int r = 0; r < 16; ++r) {
                float e = elu1(acc1[r]);
                sum += e; ss = fmaf(e, e, ss); dot = fmaf(e, g2r[r], dot);
            }
            sum += __shfl_xor(sum, 32);
            ss  += __shfl_xor(ss, 32);
            dot += __shfl_xor(dot, 32);
            float mu  = sum * 0.03125f;
            float var = fmaf(-mu, mu, ss * 0.03125f);
            float inv = rsqrtf(var + 1e-3f);
            res1 = fmaf(inv, fmaf(-mu, G, dot), C);
        }

        // lane ln covers output row b0+ln: tile0 if ln<32 (b'=lo5), tile1 if ln>=32
        lout[it & 1][ln * 5 + w] = half ? res1 : res0;
        __syncthreads();

        if (tid < 64) {
            const float* lb = lout[it & 1];
            float4 o;
            o.x = lb[tid * 5 + 0];
            o.y = lb[tid * 5 + 1];
            o.z = lb[tid * 5 + 2];
            o.w = lb[tid * 5 + 3];
            *(float4*)(out + (size_t)(b0 + tid) * 128 + qt * 4) = o;
        }

        xa = na; xb = nb;
    }
}

extern "C" void kernel_launch(void* const* d_in, const int* in_sizes, int n_in,
                              void* d_out, int out_size, void* d_ws, size_t ws_size,
                              hipStream_t stream) {
    const float* x     = (const float*)d_in[0];
    const float* W1    = (const float*)d_in[1];
    const float* b1    = (const float*)d_in[2];
    const float* gamma = (const float*)d_in[3];
    const float* beta  = (const float*)d_in[4];
    const float* W2    = (const float*)d_in[5];
    const float* b2    = (const float*)d_in[6];
    float* out = (float*)d_out;

    dim3 grid(32, 32);   // (b-tile groups, q-tiles)
    divenc_mfma<<<grid, 256, 0, stream>>>(x, W1, b1, gamma, beta, W2, b2, out);
}